// Round 1
// baseline (134.547 us; speedup 1.0000x reference)
//
#include <hip/hip_runtime.h>
#include <hip/hip_bf16.h>

#define N_TOKENS   262144
#define DIM        64
#define KCODES     512
#define OUT_ELEMS  (N_TOKENS * DIM)          // 16777216
#define LOSS_SCALE (1.25f / 16777216.0f)
#define LDS_STRIDE 72                         // 64 + 8 pad: 144B row stride -> 2-way bank alias (free)

typedef float  f32x4 __attribute__((ext_vector_type(4)));
typedef float  f32x8 __attribute__((ext_vector_type(8)));
typedef short  s16x8 __attribute__((ext_vector_type(8)));
typedef unsigned short u16x8 __attribute__((ext_vector_type(8)));

static __device__ __forceinline__ unsigned short f2bf(float f) {
    unsigned int u = __builtin_bit_cast(unsigned int, f);
    u += 0x7fffu + ((u >> 16) & 1u);          // round-to-nearest-even
    return (unsigned short)(u >> 16);
}

// Pre-kernel: codebook fp32 -> bf16 (ws), ||c||^2 fp32 (ws), zero loss slot.
__global__ void vq_prep(const float* __restrict__ cb,
                        unsigned short* __restrict__ cb_bf16,
                        float* __restrict__ c2,
                        float* __restrict__ out_loss) {
    const int k = blockIdx.x;       // 512 blocks
    const int d = threadIdx.x;      // 64 threads (one wave)
    float v = cb[k * DIM + d];
    cb_bf16[k * DIM + d] = f2bf(v);
    float s = v * v;
    #pragma unroll
    for (int sh = 1; sh < 64; sh <<= 1) s += __shfl_xor(s, sh, 64);
    if (d == 0) c2[k] = s;
    if (k == 0 && d == 0) *out_loss = 0.0f;
}

// Main kernel: 4 waves x 32 tokens = 128 tokens per block.
__global__ __launch_bounds__(256) void vq_main(
    const float* __restrict__ z,
    const float* __restrict__ cb,              // fp32 codebook (exact gather)
    const unsigned short* __restrict__ cb_bf16,
    const float* __restrict__ c2g,
    float* __restrict__ out)
{
    __shared__ unsigned short cbs[KCODES * LDS_STRIDE];  // 73728 B
    __shared__ float c2s[KCODES];                        // 2048 B
    __shared__ int   idxs[4][32];                        // 512 B

    const int tid  = threadIdx.x;
    const int wave = tid >> 6;
    const int lane = tid & 63;
    const int li   = lane & 15;   // MFMA row (A) / col (B) lane index
    const int hi   = lane >> 4;   // k-group

    // ---- stage codebook bf16 into LDS (padded rows) ----
    #pragma unroll
    for (int i = 0; i < 16; ++i) {
        const int e = (i * 256 + tid) * 8;    // 4096 x 8-elem chunks
        const int code = e >> 6, d = e & 63;
        u16x8 v = *(const u16x8*)(cb_bf16 + e);
        *(u16x8*)(&cbs[code * LDS_STRIDE + d]) = v;
    }
    for (int i = tid; i < KCODES; i += 256) c2s[i] = c2g[i];
    __syncthreads();

    const int token0 = blockIdx.x * 128 + wave * 32;

    // ---- load z (fp32, kept for loss) and build bf16 A-fragments ----
    f32x8 zv[2][2];
    s16x8 af[2][2];
    #pragma unroll
    for (int m = 0; m < 2; ++m) {
        #pragma unroll
        for (int kk = 0; kk < 2; ++kk) {
            const float* p = z + (size_t)(token0 + m * 16 + li) * DIM + kk * 32 + hi * 8;
            f32x8 v = *(const f32x8*)p;
            zv[m][kk] = v;
            s16x8 a;
            #pragma unroll
            for (int j = 0; j < 8; ++j) a[j] = (short)f2bf(v[j]);
            af[m][kk] = a;
        }
    }

    // ---- argmin over 512 codes via 32 column-tiles ----
    float best[2][4];
    int   bidx[2][4];
    #pragma unroll
    for (int m = 0; m < 2; ++m)
        #pragma unroll
        for (int r = 0; r < 4; ++r) { best[m][r] = 3.0e38f; bidx[m][r] = 0; }

    #pragma unroll 4
    for (int t = 0; t < 32; ++t) {
        const int code = t * 16 + li;
        const unsigned short* bp = &cbs[code * LDS_STRIDE + hi * 8];
        const s16x8 b0 = *(const s16x8*)(bp);        // k = 0..31 slice
        const s16x8 b1 = *(const s16x8*)(bp + 32);   // k = 32..63 slice
        const float cv = c2s[code];
        #pragma unroll
        for (int m = 0; m < 2; ++m) {
            f32x4 acc = {0.f, 0.f, 0.f, 0.f};
            acc = __builtin_amdgcn_mfma_f32_16x16x32_bf16(af[m][0], b0, acc, 0, 0, 0);
            acc = __builtin_amdgcn_mfma_f32_16x16x32_bf16(af[m][1], b1, acc, 0, 0, 0);
            // C/D layout: col = lane&15 (code), row = (lane>>4)*4 + r (token)
            #pragma unroll
            for (int r = 0; r < 4; ++r) {
                const float dist = __builtin_fmaf(-2.0f, acc[r], cv);  // ||c||^2 - 2 z.c
                if (dist < best[m][r]) { best[m][r] = dist; bidx[m][r] = code; }
            }
        }
    }

    // ---- reduce argmin across the 16 lanes sharing hi ----
    #pragma unroll
    for (int sh = 1; sh < 16; sh <<= 1) {
        #pragma unroll
        for (int m = 0; m < 2; ++m) {
            #pragma unroll
            for (int r = 0; r < 4; ++r) {
                const float ov = __shfl_xor(best[m][r], sh, 64);
                const int   oi = __shfl_xor(bidx[m][r], sh, 64);
                if (ov < best[m][r] || (ov == best[m][r] && oi < bidx[m][r])) {
                    best[m][r] = ov; bidx[m][r] = oi;
                }
            }
        }
    }

    // rows m*16 + hi*4 + r -> idx; broadcast via LDS
    if (li == 0) {
        #pragma unroll
        for (int m = 0; m < 2; ++m)
            #pragma unroll
            for (int r = 0; r < 4; ++r)
                idxs[wave][m * 16 + hi * 4 + r] = bidx[m][r];
    }
    __syncthreads();

    // ---- gather exact fp32 codebook rows, write z_q, accumulate loss ----
    float lossp = 0.f;
    #pragma unroll
    for (int m = 0; m < 2; ++m) {
        const int row  = m * 16 + li;
        const int idxr = idxs[wave][row];
        const float* cbr = cb + (size_t)idxr * DIM + hi * 8;
        #pragma unroll
        for (int kk = 0; kk < 2; ++kk) {
            const f32x8 q = *(const f32x8*)(cbr + kk * 32);
            *(f32x8*)(out + (size_t)(token0 + row) * DIM + kk * 32 + hi * 8) = q;
            #pragma unroll
            for (int j = 0; j < 8; ++j) {
                const float dfv = q[j] - zv[m][kk][j];
                lossp += dfv * dfv;
            }
        }
    }
    #pragma unroll
    for (int sh = 1; sh < 64; sh <<= 1) lossp += __shfl_xor(lossp, sh, 64);
    if (lane == 0) atomicAdd(out + OUT_ELEMS, lossp * LOSS_SCALE);
}

extern "C" void kernel_launch(void* const* d_in, const int* in_sizes, int n_in,
                              void* d_out, int out_size, void* d_ws, size_t ws_size,
                              hipStream_t stream) {
    const float* z  = (const float*)d_in[0];
    const float* cb = (const float*)d_in[1];
    float* out = (float*)d_out;

    unsigned short* cb_bf16 = (unsigned short*)d_ws;                      // 64 KiB
    float* c2 = (float*)((char*)d_ws + KCODES * DIM * sizeof(unsigned short)); // 2 KiB

    vq_prep<<<KCODES, 64, 0, stream>>>(cb, cb_bf16, c2, out + OUT_ELEMS);
    vq_main<<<N_TOKENS / 128, 256, 0, stream>>>(z, cb, cb_bf16, c2, out);
}

// Round 2
// 39.837 us; speedup vs baseline: 3.3774x; 3.3774x over previous
//
#include <hip/hip_runtime.h>
#include <hip/hip_bf16.h>

#define N_TOKENS   262144
#define DIM        64
#define KCODES     512
#define OUT_ELEMS  (N_TOKENS * DIM)          // 16777216
#define LOSS_SCALE (1.25f / 16777216.0f)

typedef float  f32x4 __attribute__((ext_vector_type(4)));
typedef float  f32x8 __attribute__((ext_vector_type(8)));
typedef short  s16x8 __attribute__((ext_vector_type(8)));
typedef unsigned short u16x8 __attribute__((ext_vector_type(8)));

static __device__ __forceinline__ unsigned short f2bf(float f) {
    unsigned int u = __builtin_bit_cast(unsigned int, f);
    u += 0x7fffu + ((u >> 16) & 1u);          // round-to-nearest-even
    return (unsigned short)(u >> 16);
}

// Prep: codebook -> bf16(-2c) in MFMA-fragment order (ws), ||c||^2+2 (ws), zero loss.
// Fragment slot for (code k, dim d):
//   t=k>>4, li=k&15, kk=d>>5, hi=(d>>3)&3, j=d&7, lane=hi*16+li
//   slot = (t*2+kk)*64 + lane ; ws element = slot*8 + j
__global__ void vq_prep(const float* __restrict__ cb,
                        unsigned short* __restrict__ cbf,
                        float* __restrict__ c2,
                        float* __restrict__ out_loss) {
    const int k = blockIdx.x;       // 512 blocks, one code each
    const int d = threadIdx.x;      // 64 threads (one wave)
    const float v = cb[k * DIM + d];
    float s = v * v;
    #pragma unroll
    for (int sh = 1; sh < 64; sh <<= 1) s += __shfl_xor(s, sh, 64);
    if (d == 0) c2[k] = s + 2.0f;                 // bias so dist+2 > 0 always

    const int t = k >> 4, li = k & 15;
    const int kk = d >> 5, hi = (d >> 3) & 3, j = d & 7;
    const int slot = (t * 2 + kk) * 64 + hi * 16 + li;
    cbf[slot * 8 + j] = f2bf(-2.0f * v);

    if (k == 0 && d == 0) *out_loss = 0.0f;
}

// Main: 8 waves x 64 tokens = 512 tokens/block, 512 blocks (2/CU exactly).
__global__ __launch_bounds__(512, 4) void vq_main(
    const float* __restrict__ z,
    const float* __restrict__ cb,              // fp32 codebook (exact gather)
    const unsigned short* __restrict__ cbf,    // bf16(-2c), fragment order
    const float* __restrict__ c2g,             // ||c||^2 + 2
    float* __restrict__ out)
{
    __shared__ unsigned short cbs[KCODES * DIM];   // 64 KiB, fragment order
    __shared__ float c2s[KCODES];                  // 2 KiB
    __shared__ int   keysl[8][64];                 // 2 KiB
    __shared__ float lpart[8];

    const int tid  = threadIdx.x;
    const int wave = tid >> 6;
    const int lane = tid & 63;
    const int li   = lane & 15;   // A-row / C-col lane index
    const int hi   = lane >> 4;   // k-group

    // ---- stage fragment-ordered codebook: pure linear copy, conflict-free ----
    #pragma unroll
    for (int i = 0; i < 8; ++i) {
        ((u16x8*)cbs)[i * 512 + tid] = ((const u16x8*)cbf)[i * 512 + tid];
    }
    c2s[tid] = c2g[tid];   // tid < 512 == KCODES
    __syncthreads();

    const int token0 = blockIdx.x * 512 + wave * 64;

    // ---- load z, build bf16 A-fragments, compute ||z||^2 per row ----
    s16x8 af[4][2];
    float z2[4];
    #pragma unroll
    for (int m = 0; m < 4; ++m) {
        float zs = 0.f;
        #pragma unroll
        for (int kk = 0; kk < 2; ++kk) {
            const float* p = z + (size_t)(token0 + m * 16 + li) * DIM + kk * 32 + hi * 8;
            const f32x8 v = *(const f32x8*)p;
            s16x8 a;
            #pragma unroll
            for (int j = 0; j < 8; ++j) {
                zs += v[j] * v[j];
                a[j] = (short)f2bf(v[j]);
            }
            af[m][kk] = a;
        }
        zs += __shfl_xor(zs, 16, 64);
        zs += __shfl_xor(zs, 32, 64);
        z2[m] = zs;   // full row sum, replicated across hi-group
    }

    // ---- argmin over 512 codes: dist emerges from MFMA (acc init = ||c||^2+2) ----
    unsigned bkey[4][4];
    #pragma unroll
    for (int m = 0; m < 4; ++m)
        #pragma unroll
        for (int r = 0; r < 4; ++r) bkey[m][r] = 0xFFFFFFFFu;

    #pragma unroll 2
    for (int t = 0; t < 32; ++t) {
        const s16x8 b0 = *(const s16x8*)&cbs[((t * 2 + 0) * 64 + lane) * 8];
        const s16x8 b1 = *(const s16x8*)&cbs[((t * 2 + 1) * 64 + lane) * 8];
        const float cv2 = c2s[t * 16 + li];
        const unsigned code = (unsigned)(t * 16 + li);
        #pragma unroll
        for (int m = 0; m < 4; ++m) {
            f32x4 acc = {cv2, cv2, cv2, cv2};
            acc = __builtin_amdgcn_mfma_f32_16x16x32_bf16(af[m][0], b0, acc, 0, 0, 0);
            acc = __builtin_amdgcn_mfma_f32_16x16x32_bf16(af[m][1], b1, acc, 0, 0, 0);
            // acc[r] = ||c||^2 + 2 - 2 z.c  for row (hi*4+r), col code  (all > 0)
            #pragma unroll
            for (int r = 0; r < 4; ++r) {
                const unsigned key = (__builtin_bit_cast(unsigned, acc[r]) & ~511u) | code;
                if (key < bkey[m][r]) bkey[m][r] = key;   // uint order == float order (>0)
            }
        }
    }

    // ---- reduce across the 16 li-lanes (positive-float keys: uint min) ----
    #pragma unroll
    for (int sh = 1; sh < 16; sh <<= 1) {
        #pragma unroll
        for (int m = 0; m < 4; ++m)
            #pragma unroll
            for (int r = 0; r < 4; ++r) {
                const unsigned ok = (unsigned)__shfl_xor((int)bkey[m][r], sh, 64);
                if (ok < bkey[m][r]) bkey[m][r] = ok;
            }
    }

    if (li == 0) {
        #pragma unroll
        for (int m = 0; m < 4; ++m)
            #pragma unroll
            for (int r = 0; r < 4; ++r)
                keysl[wave][m * 16 + hi * 4 + r] = (int)bkey[m][r];
    }
    __syncthreads();

    // ---- gather exact fp32 rows, write z_q, loss from winning key + ||z||^2 ----
    float lossp = 0.f;
    #pragma unroll
    for (int m = 0; m < 4; ++m) {
        const unsigned key = (unsigned)keysl[wave][m * 16 + li];   // row = m*16+li
        const int code = (int)(key & 511u);
        if (hi == 0)
            lossp += (__builtin_bit_cast(float, key & ~511u) - 2.0f) + z2[m];
        const float* cbr = cb + code * DIM + hi * 8;
        const f32x8 q0 = *(const f32x8*)(cbr);
        const f32x8 q1 = *(const f32x8*)(cbr + 32);
        float* op = out + (size_t)(token0 + m * 16 + li) * DIM + hi * 8;
        *(f32x8*)(op)      = q0;
        *(f32x8*)(op + 32) = q1;
    }
    #pragma unroll
    for (int sh = 1; sh < 64; sh <<= 1) lossp += __shfl_xor(lossp, sh, 64);
    if (lane == 0) lpart[wave] = lossp;
    __syncthreads();
    if (tid == 0) {
        float s = 0.f;
        #pragma unroll
        for (int w = 0; w < 8; ++w) s += lpart[w];
        atomicAdd(out + OUT_ELEMS, s * LOSS_SCALE);
    }
}

extern "C" void kernel_launch(void* const* d_in, const int* in_sizes, int n_in,
                              void* d_out, int out_size, void* d_ws, size_t ws_size,
                              hipStream_t stream) {
    const float* z  = (const float*)d_in[0];
    const float* cb = (const float*)d_in[1];
    float* out = (float*)d_out;

    unsigned short* cbf = (unsigned short*)d_ws;                               // 64 KiB
    float* c2 = (float*)((char*)d_ws + KCODES * DIM * sizeof(unsigned short)); // 2 KiB

    vq_prep<<<KCODES, 64, 0, stream>>>(cb, cbf, c2, out + OUT_ELEMS);
    vq_main<<<N_TOKENS / 512, 512, 0, stream>>>(z, cb, cbf, c2, out);
}